// Round 11
// baseline (184.038 us; speedup 1.0000x reference)
//
#include <hip/hip_runtime.h>
#include <hip/hip_bf16.h>

using short8 = __attribute__((ext_vector_type(8))) short;   // 8 x bf16 bits
using f32x4  = __attribute__((ext_vector_type(4))) float;
using uint4v = __attribute__((ext_vector_type(4))) unsigned;

#if __has_builtin(__builtin_amdgcn_exp2f)
#define EXP2(x) __builtin_amdgcn_exp2f(x)
#else
#define EXP2(x) exp2f(x)
#endif

__device__ __forceinline__ short f2bf(float f) {
    union { float f; unsigned u; } v; v.f = f;
    unsigned r = v.u + 0x7fffu + ((v.u >> 16) & 1u);
    return (short)(r >> 16);
}
// pack two fp32 -> two bf16 (truncation): result = (trunc(b)<<16) | trunc(a)
__device__ __forceinline__ unsigned pack_trunc(float a, float b) {
    union { float f; unsigned u; } ua, ub; ua.f = a; ub.f = b;
#if __has_builtin(__builtin_amdgcn_perm)
    return __builtin_amdgcn_perm(ub.u, ua.u, 0x07060302u);
#else
    return (ub.u & 0xFFFF0000u) | (ua.u >> 16);
#endif
}
__device__ __forceinline__ void async_copy16(const short* g, short* s) {
    __builtin_amdgcn_global_load_lds(
        (const __attribute__((address_space(1))) void*)g,
        (__attribute__((address_space(3))) void*)s, 16, 0, 0);
}

// ---------------------------------------------------------------------------
// fp32 -> bf16 conversion: 5 segments (x, Wq, Wk, Wv, Wo). 4 floats/thread.
// ---------------------------------------------------------------------------
__global__ __launch_bounds__(256) void cvt_f32_bf16(
    const float* __restrict__ s0, const float* __restrict__ s1,
    const float* __restrict__ s2, const float* __restrict__ s3,
    const float* __restrict__ s4,
    short* __restrict__ d0, short* __restrict__ d1, short* __restrict__ d2,
    short* __restrict__ d3, short* __restrict__ d4,
    int n0, int n1, int n2, int n3, int n4) {
    const float* s; short* d; int n;
    switch (blockIdx.y) {
        case 0: s = s0; d = d0; n = n0; break;
        case 1: s = s1; d = d1; n = n1; break;
        case 2: s = s2; d = d2; n = n2; break;
        case 3: s = s3; d = d3; n = n3; break;
        default: s = s4; d = d4; n = n4; break;
    }
    const int idx = (blockIdx.x * 256 + threadIdx.x) * 4;
    if (idx < n) {
        float4 v = *(const float4*)(s + idx);
        short4 o;
        o.x = f2bf(v.x); o.y = f2bf(v.y); o.z = f2bf(v.z); o.w = f2bf(v.w);
        *(short4*)(d + idx) = o;
    }
}

// ---------------------------------------------------------------------------
// GEMM: bf16 in, fp32 accum. A[M,K] @ B[N,K]^T. M=4096, N=K=1024.
// 128x128 tile, BK=64 (16 iters, half the barrier drains of BK=32).
// LDS layout: slot s of row r holds global 16B chunk s^(r&7) (global-side
// xor swizzle — global_load_lds dest must stay lane-linear, m104/m108).
// Fragment reads use ((kk*4+quad)^xr): 2-way max = free (attn-measured).
// MODE 0: bf16 out [M,N], scaled.
// MODE 2: bf16 out TRANSPOSED as VT[b][N][s] (b = row>>11, s = row&2047).
// ---------------------------------------------------------------------------
template <int MODE>
__device__ __forceinline__ void gemm_body(const short* __restrict__ A,
                                          const short* __restrict__ B,
                                          short* __restrict__ C,
                                          float scale) {
    constexpr int Kd = 1024, Nd = 1024, Sd = 2048;
    __shared__ __align__(16) short As[128 * 64];
    __shared__ __align__(16) short Bs[128 * 64];

    const int tid  = threadIdx.x;
    const int w    = tid >> 6, lane = tid & 63;
    const int quad = lane >> 4, l16 = lane & 15;
    const int xr   = l16 & 7;
    const int wm   = (w >> 1) * 64, wn = (w & 1) * 64;
    const int bm   = blockIdx.y * 128, bn = blockIdx.x * 128;

    f32x4 acc[4][4];
#pragma unroll
    for (int i = 0; i < 4; ++i)
#pragma unroll
        for (int j = 0; j < 4; ++j) acc[i][j] = (f32x4){0.f, 0.f, 0.f, 0.f};

    for (int k0 = 0; k0 < Kd; k0 += 64) {
        __syncthreads();
#pragma unroll
        for (int c = 0; c < 4; ++c) {
            int li   = c * 256 + tid;
            int row  = li >> 3;                    // 0..127
            int gcol = ((li & 7) ^ (row & 7)) * 8; // permuted global chunk
            async_copy16(A + (size_t)(bm + row) * Kd + k0 + gcol, &As[li * 8]);
            async_copy16(B + (size_t)(bn + row) * Kd + k0 + gcol, &Bs[li * 8]);
        }
        __syncthreads();

#pragma unroll
        for (int kk = 0; kk < 2; ++kk) {
            short8 af[4], bfv[4];
#pragma unroll
            for (int mi = 0; mi < 4; ++mi) {
                const int r = wm + mi * 16 + l16;
                af[mi] = *(const short8*)(
                    &As[r * 64 + (((kk * 4 + quad) ^ xr) * 8)]);
            }
#pragma unroll
            for (int ni = 0; ni < 4; ++ni) {
                const int r = wn + ni * 16 + l16;
                bfv[ni] = *(const short8*)(
                    &Bs[r * 64 + (((kk * 4 + quad) ^ xr) * 8)]);
            }
#pragma unroll
            for (int mi = 0; mi < 4; ++mi)
#pragma unroll
                for (int ni = 0; ni < 4; ++ni) {
                    if constexpr (MODE == 2)
                        acc[mi][ni] = __builtin_amdgcn_mfma_f32_16x16x32_bf16(
                            bfv[ni], af[mi], acc[mi][ni], 0, 0, 0);
                    else
                        acc[mi][ni] = __builtin_amdgcn_mfma_f32_16x16x32_bf16(
                            af[mi], bfv[ni], acc[mi][ni], 0, 0, 0);
                }
        }
    }

    if constexpr (MODE == 2) {
        // D rows (quad*4+r) index B-rows (e dim); D cols (l16) index A-rows (seq)
#pragma unroll
        for (int mi = 0; mi < 4; ++mi) {
            const int m_g = bm + wm + mi * 16 + l16;      // global x-row
            const int b_  = m_g >> 11, s_ = m_g & 2047;
#pragma unroll
            for (int ni = 0; ni < 4; ++ni)
#pragma unroll
                for (int r = 0; r < 4; ++r) {
                    const int n_g = bn + wn + ni * 16 + quad * 4 + r;
                    C[(size_t)b_ * Nd * Sd + (size_t)n_g * Sd + s_] =
                        f2bf(acc[mi][ni][r]);
                }
        }
    } else {
#pragma unroll
        for (int ni = 0; ni < 4; ++ni) {
            const int colg = bn + wn + ni * 16 + l16;
#pragma unroll
            for (int mi = 0; mi < 4; ++mi)
#pragma unroll
                for (int r = 0; r < 4; ++r) {
                    const int rowg = bm + wm + mi * 16 + quad * 4 + r;
                    C[(size_t)rowg * Nd + colg] = f2bf(acc[mi][ni][r] * scale);
                }
        }
    }
}

// csc = d^-0.5 * log2(e), folded into Q so attn does exp2(S) directly
#define CSC 0.18033688f

__global__ __launch_bounds__(256, 3) void proj_gemm(
    const short* __restrict__ X,
    const short* __restrict__ Wq, const short* __restrict__ Wk,
    const short* __restrict__ Wv,
    short* __restrict__ Qo, short* __restrict__ Ko, short* __restrict__ VTo) {
    if (blockIdx.z == 0)
        gemm_body<0>(X, Wq, Qo, CSC);
    else if (blockIdx.z == 1)
        gemm_body<0>(X, Wk, Ko, 1.0f);
    else
        gemm_body<2>(X, Wv, VTo, 1.0f);
}

// ---------------------------------------------------------------------------
// out_gemm: C[4096,1024] fp32 = A @ W^T + bias. 64(M)x128(N) tiles, BK=64 ->
// grid(8,64) = 512 blocks (2/CU, 2 waves/SIMD). 4 waves of 32x64 (acc 2x4).
// ---------------------------------------------------------------------------
__global__ __launch_bounds__(256, 2) void out_gemm(
    const short* __restrict__ A, const short* __restrict__ B,
    const float* __restrict__ bias, float* __restrict__ C) {
    constexpr int Kd = 1024, Nd = 1024;
    __shared__ __align__(16) short As[64 * 64];
    __shared__ __align__(16) short Bs[128 * 64];

    const int tid  = threadIdx.x;
    const int w    = tid >> 6, lane = tid & 63;
    const int quad = lane >> 4, l16 = lane & 15;
    const int xr   = l16 & 7;
    const int wm   = (w >> 1) * 32, wn = (w & 1) * 64;
    const int bm   = blockIdx.y * 64, bn = blockIdx.x * 128;

    f32x4 acc[2][4];
#pragma unroll
    for (int i = 0; i < 2; ++i)
#pragma unroll
        for (int j = 0; j < 4; ++j) acc[i][j] = (f32x4){0.f, 0.f, 0.f, 0.f};

    for (int k0 = 0; k0 < Kd; k0 += 64) {
        __syncthreads();
#pragma unroll
        for (int c = 0; c < 2; ++c) {
            int li   = c * 256 + tid;
            int row  = li >> 3;                    // 0..63
            int gcol = ((li & 7) ^ (row & 7)) * 8;
            async_copy16(A + (size_t)(bm + row) * Kd + k0 + gcol, &As[li * 8]);
        }
#pragma unroll
        for (int c = 0; c < 4; ++c) {
            int li   = c * 256 + tid;
            int row  = li >> 3;                    // 0..127
            int gcol = ((li & 7) ^ (row & 7)) * 8;
            async_copy16(B + (size_t)(bn + row) * Kd + k0 + gcol, &Bs[li * 8]);
        }
        __syncthreads();

#pragma unroll
        for (int kk = 0; kk < 2; ++kk) {
            short8 af[2], bfv[4];
#pragma unroll
            for (int mi = 0; mi < 2; ++mi) {
                const int r = wm + mi * 16 + l16;
                af[mi] = *(const short8*)(
                    &As[r * 64 + (((kk * 4 + quad) ^ xr) * 8)]);
            }
#pragma unroll
            for (int ni = 0; ni < 4; ++ni) {
                const int r = wn + ni * 16 + l16;
                bfv[ni] = *(const short8*)(
                    &Bs[r * 64 + (((kk * 4 + quad) ^ xr) * 8)]);
            }
#pragma unroll
            for (int mi = 0; mi < 2; ++mi)
#pragma unroll
                for (int ni = 0; ni < 4; ++ni)
                    acc[mi][ni] = __builtin_amdgcn_mfma_f32_16x16x32_bf16(
                        af[mi], bfv[ni], acc[mi][ni], 0, 0, 0);
        }
    }

#pragma unroll
    for (int ni = 0; ni < 4; ++ni) {
        const int colg = bn + wn + ni * 16 + l16;
        const float bv = bias[colg];
#pragma unroll
        for (int mi = 0; mi < 2; ++mi)
#pragma unroll
            for (int r = 0; r < 4; ++r) {
                const int rowg = bm + wm + mi * 16 + quad * 4 + r;
                C[(size_t)rowg * Nd + colg] = acc[mi][ni][r] + bv;
            }
    }
}

// ---------------------------------------------------------------------------
// Flash attention, no-max softmax (round-6 winner, restored verbatim).
// Q pre-scaled by CSC. Q/K: [b*s, e] bf16.  VT: [b][e][s] bf16.
// 128 q/block, 32 q/wave, 4 waves (2 waves/SIMD — required for MFMA/VALU
// cross-wave overlap; 64 q/wave at 1 wave/SIMD and key-split both regressed).
// S^T via operand-swapped MFMA. P stays in registers via permuted key order
// (slot key = 32ks + 16(j>>2) + 4quad + (j&3)); Vs staged in matching order.
// K/V LDS double-buffered -> single barrier per K-tile.
// ---------------------------------------------------------------------------
__global__ __launch_bounds__(256, 2) void attn_kernel(
    const short* __restrict__ Q, const short* __restrict__ K,
    const short* __restrict__ VT, short* __restrict__ O) {
    constexpr int S = 2048, E = 1024, NT = S / 64;
    __shared__ __align__(16) short Ks[2][64 * 64];
    __shared__ __align__(16) short Vs[2][64 * 64];

    const int tid  = threadIdx.x;
    const int w    = tid >> 6, lane = tid & 63;
    const int quad = lane >> 4, l16 = lane & 15;
    const int bh   = blockIdx.y, b = bh >> 4, h = bh & 15;
    const int qt   = blockIdx.x;

    const int    q0   = qt * 128 + w * 32;
    const size_t base = (size_t)b * S * E;
    const size_t vtb  = (size_t)b * E * S;
    const int    hc   = h * 64;
    const int    xr   = l16 & 7;

    // Q fragments (B-operand: n=query=l16, k=dim=quad*8+j), 2 query groups
    short8 aq[2][2];
#pragma unroll
    for (int qg = 0; qg < 2; ++qg) {
        const short* qp = Q + base + (size_t)(q0 + qg * 16 + l16) * E + hc + quad * 8;
        aq[qg][0] = *(const short8*)(qp);
        aq[qg][1] = *(const short8*)(qp + 32);
    }

    f32x4 oT[2][4], o_sum[2];
#pragma unroll
    for (int qg = 0; qg < 2; ++qg) {
        o_sum[qg] = (f32x4){0.f, 0.f, 0.f, 0.f};
#pragma unroll
        for (int i = 0; i < 4; ++i) oT[qg][i] = (f32x4){0.f, 0.f, 0.f, 0.f};
    }

    // staging: li = c*256+tid -> row=li>>3 (0..63), cc=li&7 (16B chunk).
    // K: xor-swizzled chunks. V: permuted key order, split into two b64.
    int          kdst[2], vdst0[2], vdst1[2];
    const short* kga[2];
    const short* vga[2];
#pragma unroll
    for (int c = 0; c < 2; ++c) {
        int li = c * 256 + tid, row = li >> 3, cc = li & 7;
        kdst[c] = row * 64 + ((cc ^ (row & 7)) * 8);
        int c0   = 4 * (cc >> 2) + 2 * (cc & 1);   // phys chunk of keys cc*8..+3
        int boff = 4 * ((cc >> 1) & 1);            // within-chunk half
        vdst0[c] = row * 64 + ((c0 ^ (row & 7)) * 8) + boff;
        vdst1[c] = row * 64 + (((c0 + 1) ^ (row & 7)) * 8) + boff;
        kga[c]   = K + base + (size_t)row * E + hc + cc * 8;
        vga[c]   = VT + vtb + (size_t)(hc + row) * S + cc * 8;
    }

    short8 kr[2], vr[2];
#pragma unroll
    for (int c = 0; c < 2; ++c) {       // tile 0 -> regs
        kr[c] = *(const short8*)(kga[c]);
        vr[c] = *(const short8*)(vga[c]);
    }
#pragma unroll
    for (int c = 0; c < 2; ++c) {       // regs -> buf 0
        *(short8*)(&Ks[0][kdst[c]]) = kr[c];
        short4 lo, hi;
        lo.x = vr[c][0]; lo.y = vr[c][1]; lo.z = vr[c][2]; lo.w = vr[c][3];
        hi.x = vr[c][4]; hi.y = vr[c][5]; hi.z = vr[c][6]; hi.w = vr[c][7];
        *(short4*)(&Vs[0][vdst0[c]]) = lo;
        *(short4*)(&Vs[0][vdst1[c]]) = hi;
    }
#pragma unroll
    for (int c = 0; c < 2; ++c) {       // tile 1 -> regs
        kr[c] = *(const short8*)(kga[c] + (size_t)64 * E);
        vr[c] = *(const short8*)(vga[c] + 64);
    }
    __syncthreads();

    const short8 ones = (short8){0x3F80, 0x3F80, 0x3F80, 0x3F80,
                                 0x3F80, 0x3F80, 0x3F80, 0x3F80};
    const float  LB   = 0.00281502f;   // log2(1 + 2^-9): centers P truncation

    for (int kt = 0; kt < NT; ++kt) {
        const int    cur = kt & 1;
        const short* Kc  = Ks[cur];
        const short* Vc  = Vs[cur];

        if (kt + 1 < NT) {   // regs (tile kt+1) -> other buffer
            short* Kn = Ks[cur ^ 1];
            short* Vn = Vs[cur ^ 1];
#pragma unroll
            for (int c = 0; c < 2; ++c) {
                *(short8*)(&Kn[kdst[c]]) = kr[c];
                short4 lo, hi;
                lo.x = vr[c][0]; lo.y = vr[c][1]; lo.z = vr[c][2]; lo.w = vr[c][3];
                hi.x = vr[c][4]; hi.y = vr[c][5]; hi.z = vr[c][6]; hi.w = vr[c][7];
                *(short4*)(&Vn[vdst0[c]]) = lo;
                *(short4*)(&Vn[vdst1[c]]) = hi;
            }
            if (kt + 2 < NT) {   // prefetch tile kt+2 -> regs
#pragma unroll
                for (int c = 0; c < 2; ++c) {
                    kr[c] = *(const short8*)(kga[c] + (size_t)(kt + 2) * 64 * E);
                    vr[c] = *(const short8*)(vga[c] + (kt + 2) * 64);
                }
            }
        }

        // S^T = K @ Q^T; p = 2^s packed to bf16, kept in registers
        uint4v pkv[2][2];   // [qg][ks]: 4 dwords = 8 keys in permuted order
#pragma unroll
        for (int kn = 0; kn < 4; ++kn) {
            const short* kb  = &Kc[(kn * 16 + l16) * 64];
            short8       bk0 = *(const short8*)(kb + ((quad ^ xr) * 8));
            short8       bk1 = *(const short8*)(kb + (((quad + 4) ^ xr) * 8));
#pragma unroll
            for (int qg = 0; qg < 2; ++qg) {
                f32x4 a = (f32x4){LB, LB, LB, LB};
                a = __builtin_amdgcn_mfma_f32_16x16x32_bf16(bk0, aq[qg][0], a, 0, 0, 0);
                a = __builtin_amdgcn_mfma_f32_16x16x32_bf16(bk1, aq[qg][1], a, 0, 0, 0);
                pkv[qg][kn >> 1][(kn & 1) * 2]     = pack_trunc(EXP2(a[0]), EXP2(a[1]));
                pkv[qg][kn >> 1][(kn & 1) * 2 + 1] = pack_trunc(EXP2(a[2]), EXP2(a[3]));
            }
        }

        // O^T += V-frag (A: m=dim, permuted keys) @ P-frag (B: own regs)
#pragma unroll
        for (int ks = 0; ks < 2; ++ks) {
            short8 pf[2];
#pragma unroll
            for (int qg = 0; qg < 2; ++qg) {
                union { uint4v u; short8 s; } cv;
                cv.u   = pkv[qg][ks];
                pf[qg] = cv.s;
                o_sum[qg] = __builtin_amdgcn_mfma_f32_16x16x32_bf16(
                    ones, pf[qg], o_sum[qg], 0, 0, 0);
            }
#pragma unroll
            for (int ni = 0; ni < 4; ++ni) {
                const int rv = ni * 16 + l16;
                short8 vb =
                    *(const short8*)(&Vc[rv * 64 + (((ks * 4 + quad) ^ xr) * 8)]);
#pragma unroll
                for (int qg = 0; qg < 2; ++qg)
                    oT[qg][ni] = __builtin_amdgcn_mfma_f32_16x16x32_bf16(
                        vb, pf[qg], oT[qg][ni], 0, 0, 0);
            }
        }
        __syncthreads();
    }

    // epilogue: O^T C-layout: col=query=l16, row=dim=ni*16+quad*4+r
#pragma unroll
    for (int qg = 0; qg < 2; ++qg) {
        const float inv = 1.0f / o_sum[qg][0];
        const int   qg_ = q0 + qg * 16 + l16;
#pragma unroll
        for (int ni = 0; ni < 4; ++ni) {
            short4 ov;
            ov.x = f2bf(oT[qg][ni][0] * inv);
            ov.y = f2bf(oT[qg][ni][1] * inv);
            ov.z = f2bf(oT[qg][ni][2] * inv);
            ov.w = f2bf(oT[qg][ni][3] * inv);
            *(short4*)(&O[base + (size_t)qg_ * E + hc + ni * 16 + quad * 4]) = ov;
        }
    }
}

// ---------------------------------------------------------------------------
extern "C" void kernel_launch(void* const* d_in, const int* in_sizes, int n_in,
                              void* d_out, int out_size, void* d_ws, size_t ws_size,
                              hipStream_t stream) {
    const float* x  = (const float*)d_in[0];
    const float* Wq = (const float*)d_in[1];
    const float* Wk = (const float*)d_in[2];
    const float* Wv = (const float*)d_in[3];
    const float* Wo = (const float*)d_in[4];
    const float* bo = (const float*)d_in[5];
    float* out = (float*)d_out;

    constexpr int XN = 2 * 2048 * 1024;   // 4M elements
    constexpr int WN = 1024 * 1024;       // 1M elements

    short* Xb  = (short*)d_ws;     // 4M shorts; reused as attention-out buffer
    short* Wqb = Xb + XN;
    short* Wkb = Wqb + WN;
    short* Wvb = Wkb + WN;
    short* Wob = Wvb + WN;
    short* Qb  = Wob + WN;
    short* Kb  = Qb + XN;
    short* VTb = Kb + XN;          // [b][e][s]

    cvt_f32_bf16<<<dim3(4096, 5), 256, 0, stream>>>(
        x, Wq, Wk, Wv, Wo, Xb, Wqb, Wkb, Wvb, Wob, XN, WN, WN, WN, WN);
    proj_gemm<<<dim3(8, 32, 3), 256, 0, stream>>>(Xb, Wqb, Wkb, Wvb, Qb, Kb, VTb);
    attn_kernel<<<dim3(16, 32), 256, 0, stream>>>(Qb, Kb, VTb, Xb /*O*/);
    out_gemm<<<dim3(8, 64), 256, 0, stream>>>(Xb, Wob, bo, out);
}

// Round 12
// 169.885 us; speedup vs baseline: 1.0833x; 1.0833x over previous
//
#include <hip/hip_runtime.h>
#include <hip/hip_bf16.h>

using short8 = __attribute__((ext_vector_type(8))) short;   // 8 x bf16 bits
using f32x4  = __attribute__((ext_vector_type(4))) float;
using uint4v = __attribute__((ext_vector_type(4))) unsigned;

#if __has_builtin(__builtin_amdgcn_exp2f)
#define EXP2(x) __builtin_amdgcn_exp2f(x)
#else
#define EXP2(x) exp2f(x)
#endif

__device__ __forceinline__ short f2bf(float f) {
    union { float f; unsigned u; } v; v.f = f;
    unsigned r = v.u + 0x7fffu + ((v.u >> 16) & 1u);
    return (short)(r >> 16);
}
// pack two fp32 -> two bf16 (truncation): result = (trunc(b)<<16) | trunc(a)
__device__ __forceinline__ unsigned pack_trunc(float a, float b) {
    union { float f; unsigned u; } ua, ub; ua.f = a; ub.f = b;
#if __has_builtin(__builtin_amdgcn_perm)
    return __builtin_amdgcn_perm(ub.u, ua.u, 0x07060302u);
#else
    return (ub.u & 0xFFFF0000u) | (ua.u >> 16);
#endif
}
__device__ __forceinline__ void async_copy16(const short* g, short* s) {
    __builtin_amdgcn_global_load_lds(
        (const __attribute__((address_space(1))) void*)g,
        (__attribute__((address_space(3))) void*)s, 16, 0, 0);
}

// ---------------------------------------------------------------------------
// fp32 -> bf16 conversion: 5 segments (x, Wq, Wk, Wv, Wo). 4 floats/thread.
// ---------------------------------------------------------------------------
__global__ __launch_bounds__(256) void cvt_f32_bf16(
    const float* __restrict__ s0, const float* __restrict__ s1,
    const float* __restrict__ s2, const float* __restrict__ s3,
    const float* __restrict__ s4,
    short* __restrict__ d0, short* __restrict__ d1, short* __restrict__ d2,
    short* __restrict__ d3, short* __restrict__ d4,
    int n0, int n1, int n2, int n3, int n4) {
    const float* s; short* d; int n;
    switch (blockIdx.y) {
        case 0: s = s0; d = d0; n = n0; break;
        case 1: s = s1; d = d1; n = n1; break;
        case 2: s = s2; d = d2; n = n2; break;
        case 3: s = s3; d = d3; n = n3; break;
        default: s = s4; d = d4; n = n4; break;
    }
    const int idx = (blockIdx.x * 256 + threadIdx.x) * 4;
    if (idx < n) {
        float4 v = *(const float4*)(s + idx);
        short4 o;
        o.x = f2bf(v.x); o.y = f2bf(v.y); o.z = f2bf(v.z); o.w = f2bf(v.w);
        *(short4*)(d + idx) = o;
    }
}

// ---------------------------------------------------------------------------
// GEMM body: bf16 in, fp32 accum. A[M,K] @ B[N,K]^T. M=4096, N=K=1024.
// 128x128 tile, BK=64 (16 iters, half the barrier drains of BK=32).
// LDS (As/Bs, 128x64 shorts each) is OWNED BY THE CALLER — template
// instantiations must share one allocation (each static __shared__ per
// instantiation doubled LDS to 64 KB and cost a block/CU — round-11 bug).
// Layout: slot s of row r holds global 16B chunk s^(r&7) (global-side xor
// swizzle; global_load_lds dest must stay lane-linear, m104/m108).
// Fragment reads use ((kk*4+quad)^xr): measured conflict-free.
// MODE 0: bf16 out [M,N], scaled.
// MODE 2: bf16 out TRANSPOSED as VT[b][N][s] (b = row>>11, s = row&2047).
// ---------------------------------------------------------------------------
template <int MODE>
__device__ __forceinline__ void gemm_body(const short* __restrict__ A,
                                          const short* __restrict__ B,
                                          short* __restrict__ C,
                                          float scale,
                                          short* __restrict__ As,
                                          short* __restrict__ Bs) {
    constexpr int Kd = 1024, Nd = 1024, Sd = 2048;

    const int tid  = threadIdx.x;
    const int w    = tid >> 6, lane = tid & 63;
    const int quad = lane >> 4, l16 = lane & 15;
    const int xr   = l16 & 7;
    const int wm   = (w >> 1) * 64, wn = (w & 1) * 64;
    const int bm   = blockIdx.y * 128, bn = blockIdx.x * 128;

    f32x4 acc[4][4];
#pragma unroll
    for (int i = 0; i < 4; ++i)
#pragma unroll
        for (int j = 0; j < 4; ++j) acc[i][j] = (f32x4){0.f, 0.f, 0.f, 0.f};

    for (int k0 = 0; k0 < Kd; k0 += 64) {
        __syncthreads();
#pragma unroll
        for (int c = 0; c < 4; ++c) {
            int li   = c * 256 + tid;
            int row  = li >> 3;                    // 0..127
            int gcol = ((li & 7) ^ (row & 7)) * 8; // permuted global chunk
            async_copy16(A + (size_t)(bm + row) * Kd + k0 + gcol, &As[li * 8]);
            async_copy16(B + (size_t)(bn + row) * Kd + k0 + gcol, &Bs[li * 8]);
        }
        __syncthreads();

#pragma unroll
        for (int kk = 0; kk < 2; ++kk) {
            short8 af[4], bfv[4];
#pragma unroll
            for (int mi = 0; mi < 4; ++mi) {
                const int r = wm + mi * 16 + l16;
                af[mi] = *(const short8*)(
                    &As[r * 64 + (((kk * 4 + quad) ^ xr) * 8)]);
            }
#pragma unroll
            for (int ni = 0; ni < 4; ++ni) {
                const int r = wn + ni * 16 + l16;
                bfv[ni] = *(const short8*)(
                    &Bs[r * 64 + (((kk * 4 + quad) ^ xr) * 8)]);
            }
#pragma unroll
            for (int mi = 0; mi < 4; ++mi)
#pragma unroll
                for (int ni = 0; ni < 4; ++ni) {
                    if constexpr (MODE == 2)
                        acc[mi][ni] = __builtin_amdgcn_mfma_f32_16x16x32_bf16(
                            bfv[ni], af[mi], acc[mi][ni], 0, 0, 0);
                    else
                        acc[mi][ni] = __builtin_amdgcn_mfma_f32_16x16x32_bf16(
                            af[mi], bfv[ni], acc[mi][ni], 0, 0, 0);
                }
        }
    }

    if constexpr (MODE == 2) {
        // D rows (quad*4+r) index B-rows (e dim); D cols (l16) index A-rows (seq)
#pragma unroll
        for (int mi = 0; mi < 4; ++mi) {
            const int m_g = bm + wm + mi * 16 + l16;      // global x-row
            const int b_  = m_g >> 11, s_ = m_g & 2047;
#pragma unroll
            for (int ni = 0; ni < 4; ++ni)
#pragma unroll
                for (int r = 0; r < 4; ++r) {
                    const int n_g = bn + wn + ni * 16 + quad * 4 + r;
                    C[(size_t)b_ * Nd * Sd + (size_t)n_g * Sd + s_] =
                        f2bf(acc[mi][ni][r]);
                }
        }
    } else {
#pragma unroll
        for (int ni = 0; ni < 4; ++ni) {
            const int colg = bn + wn + ni * 16 + l16;
#pragma unroll
            for (int mi = 0; mi < 4; ++mi)
#pragma unroll
                for (int r = 0; r < 4; ++r) {
                    const int rowg = bm + wm + mi * 16 + quad * 4 + r;
                    C[(size_t)rowg * Nd + colg] = f2bf(acc[mi][ni][r] * scale);
                }
        }
    }
}

// csc = d^-0.5 * log2(e), folded into Q so attn does exp2(S) directly
#define CSC 0.18033688f

__global__ __launch_bounds__(256, 3) void proj_gemm(
    const short* __restrict__ X,
    const short* __restrict__ Wq, const short* __restrict__ Wk,
    const short* __restrict__ Wv,
    short* __restrict__ Qo, short* __restrict__ Ko, short* __restrict__ VTo) {
    __shared__ __align__(16) short As[128 * 64];   // single allocation shared
    __shared__ __align__(16) short Bs[128 * 64];   // by all instantiations
    if (blockIdx.z == 0)
        gemm_body<0>(X, Wq, Qo, CSC, As, Bs);
    else if (blockIdx.z == 1)
        gemm_body<0>(X, Wk, Ko, 1.0f, As, Bs);
    else
        gemm_body<2>(X, Wv, VTo, 1.0f, As, Bs);
}

// ---------------------------------------------------------------------------
// out_gemm: C[4096,1024] fp32 = A @ W^T + bias. 64(M)x128(N) tiles, BK=64 ->
// grid(8,64) = 512 blocks (2/CU, 2 waves/SIMD). 4 waves of 32x64 (acc 2x4).
// ---------------------------------------------------------------------------
__global__ __launch_bounds__(256, 2) void out_gemm(
    const short* __restrict__ A, const short* __restrict__ B,
    const float* __restrict__ bias, float* __restrict__ C) {
    constexpr int Kd = 1024, Nd = 1024;
    __shared__ __align__(16) short As[64 * 64];
    __shared__ __align__(16) short Bs[128 * 64];

    const int tid  = threadIdx.x;
    const int w    = tid >> 6, lane = tid & 63;
    const int quad = lane >> 4, l16 = lane & 15;
    const int xr   = l16 & 7;
    const int wm   = (w >> 1) * 32, wn = (w & 1) * 64;
    const int bm   = blockIdx.y * 64, bn = blockIdx.x * 128;

    f32x4 acc[2][4];
#pragma unroll
    for (int i = 0; i < 2; ++i)
#pragma unroll
        for (int j = 0; j < 4; ++j) acc[i][j] = (f32x4){0.f, 0.f, 0.f, 0.f};

    for (int k0 = 0; k0 < Kd; k0 += 64) {
        __syncthreads();
#pragma unroll
        for (int c = 0; c < 2; ++c) {
            int li   = c * 256 + tid;
            int row  = li >> 3;                    // 0..63
            int gcol = ((li & 7) ^ (row & 7)) * 8;
            async_copy16(A + (size_t)(bm + row) * Kd + k0 + gcol, &As[li * 8]);
        }
#pragma unroll
        for (int c = 0; c < 4; ++c) {
            int li   = c * 256 + tid;
            int row  = li >> 3;                    // 0..127
            int gcol = ((li & 7) ^ (row & 7)) * 8;
            async_copy16(B + (size_t)(bn + row) * Kd + k0 + gcol, &Bs[li * 8]);
        }
        __syncthreads();

#pragma unroll
        for (int kk = 0; kk < 2; ++kk) {
            short8 af[2], bfv[4];
#pragma unroll
            for (int mi = 0; mi < 2; ++mi) {
                const int r = wm + mi * 16 + l16;
                af[mi] = *(const short8*)(
                    &As[r * 64 + (((kk * 4 + quad) ^ xr) * 8)]);
            }
#pragma unroll
            for (int ni = 0; ni < 4; ++ni) {
                const int r = wn + ni * 16 + l16;
                bfv[ni] = *(const short8*)(
                    &Bs[r * 64 + (((kk * 4 + quad) ^ xr) * 8)]);
            }
#pragma unroll
            for (int mi = 0; mi < 2; ++mi)
#pragma unroll
                for (int ni = 0; ni < 4; ++ni)
                    acc[mi][ni] = __builtin_amdgcn_mfma_f32_16x16x32_bf16(
                        af[mi], bfv[ni], acc[mi][ni], 0, 0, 0);
        }
    }

#pragma unroll
    for (int ni = 0; ni < 4; ++ni) {
        const int colg = bn + wn + ni * 16 + l16;
        const float bv = bias[colg];
#pragma unroll
        for (int mi = 0; mi < 2; ++mi)
#pragma unroll
            for (int r = 0; r < 4; ++r) {
                const int rowg = bm + wm + mi * 16 + quad * 4 + r;
                C[(size_t)rowg * Nd + colg] = acc[mi][ni][r] + bv;
            }
    }
}

// ---------------------------------------------------------------------------
// Flash attention, no-max softmax (round-6 winner).
// Q pre-scaled by CSC. Q/K: [b*s, e] bf16.  VT: [b][e][s] bf16.
// 128 q/block, 32 q/wave, 4 waves (2 waves/SIMD — required for MFMA/VALU
// cross-wave overlap; 64 q/wave at 1 wave/SIMD and key-split both regressed).
// S^T via operand-swapped MFMA. P stays in registers via permuted key order
// (slot key = 32ks + 16(j>>2) + 4quad + (j&3)); Vs staged in matching order.
// K/V LDS double-buffered -> single barrier per K-tile.
// ---------------------------------------------------------------------------
__global__ __launch_bounds__(256, 2) void attn_kernel(
    const short* __restrict__ Q, const short* __restrict__ K,
    const short* __restrict__ VT, short* __restrict__ O) {
    constexpr int S = 2048, E = 1024, NT = S / 64;
    __shared__ __align__(16) short Ks[2][64 * 64];
    __shared__ __align__(16) short Vs[2][64 * 64];

    const int tid  = threadIdx.x;
    const int w    = tid >> 6, lane = tid & 63;
    const int quad = lane >> 4, l16 = lane & 15;
    const int bh   = blockIdx.y, b = bh >> 4, h = bh & 15;
    const int qt   = blockIdx.x;

    const int    q0   = qt * 128 + w * 32;
    const size_t base = (size_t)b * S * E;
    const size_t vtb  = (size_t)b * E * S;
    const int    hc   = h * 64;
    const int    xr   = l16 & 7;

    // Q fragments (B-operand: n=query=l16, k=dim=quad*8+j), 2 query groups
    short8 aq[2][2];
#pragma unroll
    for (int qg = 0; qg < 2; ++qg) {
        const short* qp = Q + base + (size_t)(q0 + qg * 16 + l16) * E + hc + quad * 8;
        aq[qg][0] = *(const short8*)(qp);
        aq[qg][1] = *(const short8*)(qp + 32);
    }

    f32x4 oT[2][4], o_sum[2];
#pragma unroll
    for (int qg = 0; qg < 2; ++qg) {
        o_sum[qg] = (f32x4){0.f, 0.f, 0.f, 0.f};
#pragma unroll
        for (int i = 0; i < 4; ++i) oT[qg][i] = (f32x4){0.f, 0.f, 0.f, 0.f};
    }

    // staging: li = c*256+tid -> row=li>>3 (0..63), cc=li&7 (16B chunk).
    // K: xor-swizzled chunks. V: permuted key order, split into two b64.
    int          kdst[2], vdst0[2], vdst1[2];
    const short* kga[2];
    const short* vga[2];
#pragma unroll
    for (int c = 0; c < 2; ++c) {
        int li = c * 256 + tid, row = li >> 3, cc = li & 7;
        kdst[c] = row * 64 + ((cc ^ (row & 7)) * 8);
        int c0   = 4 * (cc >> 2) + 2 * (cc & 1);   // phys chunk of keys cc*8..+3
        int boff = 4 * ((cc >> 1) & 1);            // within-chunk half
        vdst0[c] = row * 64 + ((c0 ^ (row & 7)) * 8) + boff;
        vdst1[c] = row * 64 + (((c0 + 1) ^ (row & 7)) * 8) + boff;
        kga[c]   = K + base + (size_t)row * E + hc + cc * 8;
        vga[c]   = VT + vtb + (size_t)(hc + row) * S + cc * 8;
    }

    short8 kr[2], vr[2];
#pragma unroll
    for (int c = 0; c < 2; ++c) {       // tile 0 -> regs
        kr[c] = *(const short8*)(kga[c]);
        vr[c] = *(const short8*)(vga[c]);
    }
#pragma unroll
    for (int c = 0; c < 2; ++c) {       // regs -> buf 0
        *(short8*)(&Ks[0][kdst[c]]) = kr[c];
        short4 lo, hi;
        lo.x = vr[c][0]; lo.y = vr[c][1]; lo.z = vr[c][2]; lo.w = vr[c][3];
        hi.x = vr[c][4]; hi.y = vr[c][5]; hi.z = vr[c][6]; hi.w = vr[c][7];
        *(short4*)(&Vs[0][vdst0[c]]) = lo;
        *(short4*)(&Vs[0][vdst1[c]]) = hi;
    }
#pragma unroll
    for (int c = 0; c < 2; ++c) {       // tile 1 -> regs
        kr[c] = *(const short8*)(kga[c] + (size_t)64 * E);
        vr[c] = *(const short8*)(vga[c] + 64);
    }
    __syncthreads();

    const short8 ones = (short8){0x3F80, 0x3F80, 0x3F80, 0x3F80,
                                 0x3F80, 0x3F80, 0x3F80, 0x3F80};
    const float  LB   = 0.00281502f;   // log2(1 + 2^-9): centers P truncation

    for (int kt = 0; kt < NT; ++kt) {
        const int    cur = kt & 1;
        const short* Kc  = Ks[cur];
        const short* Vc  = Vs[cur];

        if (kt + 1 < NT) {   // regs (tile kt+1) -> other buffer
            short* Kn = Ks[cur ^ 1];
            short* Vn = Vs[cur ^ 1];
#pragma unroll
            for (int c = 0; c < 2; ++c) {
                *(short8*)(&Kn[kdst[c]]) = kr[c];
                short4 lo, hi;
                lo.x = vr[c][0]; lo.y = vr[c][1]; lo.z = vr[c][2]; lo.w = vr[c][3];
                hi.x = vr[c][4]; hi.y = vr[c][5]; hi.z = vr[c][6]; hi.w = vr[c][7];
                *(short4*)(&Vn[vdst0[c]]) = lo;
                *(short4*)(&Vn[vdst1[c]]) = hi;
            }
            if (kt + 2 < NT) {   // prefetch tile kt+2 -> regs
#pragma unroll
                for (int c = 0; c < 2; ++c) {
                    kr[c] = *(const short8*)(kga[c] + (size_t)(kt + 2) * 64 * E);
                    vr[c] = *(const short8*)(vga[c] + (kt + 2) * 64);
                }
            }
        }

        // S^T = K @ Q^T; p = 2^s packed to bf16, kept in registers
        uint4v pkv[2][2];   // [qg][ks]: 4 dwords = 8 keys in permuted order
#pragma unroll
        for (int kn = 0; kn < 4; ++kn) {
            const short* kb  = &Kc[(kn * 16 + l16) * 64];
            short8       bk0 = *(const short8*)(kb + ((quad ^ xr) * 8));
            short8       bk1 = *(const short8*)(kb + (((quad + 4) ^ xr) * 8));
#pragma unroll
            for (int qg = 0; qg < 2; ++qg) {
                f32x4 a = (f32x4){LB, LB, LB, LB};
                a = __builtin_amdgcn_mfma_f32_16x16x32_bf16(bk0, aq[qg][0], a, 0, 0, 0);
                a = __builtin_amdgcn_mfma_f32_16x16x32_bf16(bk1, aq[qg][1], a, 0, 0, 0);
                pkv[qg][kn >> 1][(kn & 1) * 2]     = pack_trunc(EXP2(a[0]), EXP2(a[1]));
                pkv[qg][kn >> 1][(kn & 1) * 2 + 1] = pack_trunc(EXP2(a[2]), EXP2(a[3]));
            }
        }

        // O^T += V-frag (A: m=dim, permuted keys) @ P-frag (B: own regs)
#pragma unroll
        for (int ks = 0; ks < 2; ++ks) {
            short8 pf[2];
#pragma unroll
            for (int qg = 0; qg < 2; ++qg) {
                union { uint4v u; short8 s; } cv;
                cv.u   = pkv[qg][ks];
                pf[qg] = cv.s;
                o_sum[qg] = __builtin_amdgcn_mfma_f32_16x16x32_bf16(
                    ones, pf[qg], o_sum[qg], 0, 0, 0);
            }
#pragma unroll
            for (int ni = 0; ni < 4; ++ni) {
                const int rv = ni * 16 + l16;
                short8 vb =
                    *(const short8*)(&Vc[rv * 64 + (((ks * 4 + quad) ^ xr) * 8)]);
#pragma unroll
                for (int qg = 0; qg < 2; ++qg)
                    oT[qg][ni] = __builtin_amdgcn_mfma_f32_16x16x32_bf16(
                        vb, pf[qg], oT[qg][ni], 0, 0, 0);
            }
        }
        __syncthreads();
    }

    // epilogue: O^T C-layout: col=query=l16, row=dim=ni*16+quad*4+r
#pragma unroll
    for (int qg = 0; qg < 2; ++qg) {
        const float inv = 1.0f / o_sum[qg][0];
        const int   qg_ = q0 + qg * 16 + l16;
#pragma unroll
        for (int ni = 0; ni < 4; ++ni) {
            short4 ov;
            ov.x = f2bf(oT[qg][ni][0] * inv);
            ov.y = f2bf(oT[qg][ni][1] * inv);
            ov.z = f2bf(oT[qg][ni][2] * inv);
            ov.w = f2bf(oT[qg][ni][3] * inv);
            *(short4*)(&O[base + (size_t)qg_ * E + hc + ni * 16 + quad * 4]) = ov;
        }
    }
}

// ---------------------------------------------------------------------------
extern "C" void kernel_launch(void* const* d_in, const int* in_sizes, int n_in,
                              void* d_out, int out_size, void* d_ws, size_t ws_size,
                              hipStream_t stream) {
    const float* x  = (const float*)d_in[0];
    const float* Wq = (const float*)d_in[1];
    const float* Wk = (const float*)d_in[2];
    const float* Wv = (const float*)d_in[3];
    const float* Wo = (const float*)d_in[4];
    const float* bo = (const float*)d_in[5];
    float* out = (float*)d_out;

    constexpr int XN = 2 * 2048 * 1024;   // 4M elements
    constexpr int WN = 1024 * 1024;       // 1M elements

    short* Xb  = (short*)d_ws;     // 4M shorts; reused as attention-out buffer
    short* Wqb = Xb + XN;
    short* Wkb = Wqb + WN;
    short* Wvb = Wkb + WN;
    short* Wob = Wvb + WN;
    short* Qb  = Wob + WN;
    short* Kb  = Qb + XN;
    short* VTb = Kb + XN;          // [b][e][s]

    cvt_f32_bf16<<<dim3(4096, 5), 256, 0, stream>>>(
        x, Wq, Wk, Wv, Wo, Xb, Wqb, Wkb, Wvb, Wob, XN, WN, WN, WN, WN);
    proj_gemm<<<dim3(8, 32, 3), 256, 0, stream>>>(Xb, Wqb, Wkb, Wvb, Qb, Kb, VTb);
    attn_kernel<<<dim3(16, 32), 256, 0, stream>>>(Qb, Kb, VTb, Xb /*O*/);
    out_gemm<<<dim3(8, 64), 256, 0, stream>>>(Xb, Wob, bo, out);
}